// Round 1
// baseline (570.692 us; speedup 1.0000x reference)
//
#include <hip/hip_runtime.h>
#include <hip/hip_bf16.h>

// Problem constants (fixed by the reference file)
#define LEAFN 1024
#define NN    2048            // nodes per batch incl. global node 0
#define BATCH 8
#define DD    128
#define ROWS  (BATCH*NN)      // 16384

// ln(10000)/32
#define LOG1E4_OVER_32 0.28782313662425575f

__device__ __forceinline__ float enc_val(int node, int d) {
  float hp, vp;
  if (node == 0) { hp = -0.5f; vp = -1.0f; }
  else {
    int v = 31 - __clz(node);
    hp = (float)(node - (1 << v));
    vp = (float)v;
  }
  float pos = (d < 64) ? hp : vp;
  int i = ((d < 64) ? d : (d - 64)) >> 1;
  float inv = expf(-(float)i * LOG1E4_OVER_32);
  float ang = pos * inv;
  return (d & 1) ? cosf(ang) : sinf(ang);
}

// ---------------------------------------------------------------------------
// CSR segment bounds from globally-sorted dst. Node 0 of each batch has no
// incoming edges -> set empty range explicitly (ws is poisoned 0xAA).
__global__ void k_csr(const int* __restrict__ dst, int E,
                      int* __restrict__ s0, int* __restrict__ s1) {
  int i = blockIdx.x * blockDim.x + threadIdx.x;
  if (i < BATCH) { s0[i * NN] = 0; s1[i * NN] = 0; }
  if (i >= E) return;
  int dv = dst[i];
  if (i == 0 || dst[i - 1] != dv) s0[dv] = i;
  if (i == E - 1 || dst[i + 1] != dv) s1[dv] = i + 1;
}

// ---------------------------------------------------------------------------
// Each block: one 64-leaf subtree (batch b, subtree s rooted at node 16+s).
// Reduce levels 10..4 in LDS, write x (+enc) for those nodes, stash raw
// level-4 feature for k_top.
__global__ __launch_bounds__(256) void k_tree(const float* __restrict__ elements,
                                              float* __restrict__ x,
                                              float* __restrict__ lvl4) {
  __shared__ float sm[127 * DD];   // local heap nodes 1..127, row (k-1)
  int b = blockIdx.x >> 4, s = blockIdx.x & 15;
  const float4* src = (const float4*)(elements + (size_t)(b * LEAFN + s * 64) * DD);
  // load 64 leaves (local k = 64..127 -> rows 63..126)
  for (int i = threadIdx.x; i < 2048; i += 256) {   // 2048 float4s
    int f = i * 4;
    int j = f >> 7, d = f & 127;
    *(float4*)&sm[(63 + j) * DD + d] = src[i];
  }
  __syncthreads();
  for (int lv = 5; lv >= 0; --lv) {
    int nodes = 1 << lv;
    for (int idx = threadIdx.x; idx < nodes * DD; idx += 256) {
      int k = nodes + (idx >> 7);
      int d = idx & 127;
      sm[(k - 1) * DD + d] = 0.5f * (sm[(2 * k - 1) * DD + d] + sm[(2 * k) * DD + d]);
    }
    __syncthreads();
  }
  for (int idx = threadIdx.x; idx < 127 * DD; idx += 256) {
    int k = (idx >> 7) + 1;
    int d = idx & 127;
    int lv = 31 - __clz(k);
    int g = ((16 + s) << lv) | (k - (1 << lv));
    x[((size_t)(b * NN + g)) * DD + d] = sm[idx] + enc_val(g, d);
  }
  if (threadIdx.x < DD) lvl4[(b * 16 + s) * DD + threadIdx.x] = sm[threadIdx.x];
}

// ---------------------------------------------------------------------------
// Finish nodes 0..15 per batch from the 16 level-4 feats.
__global__ void k_top(const float* __restrict__ lvl4, float* __restrict__ x) {
  int b = blockIdx.x, d = threadIdx.x;   // 128 threads
  float v[16];
  for (int j = 0; j < 16; ++j) v[j] = lvl4[(b * 16 + j) * DD + d];
  for (int j = 0; j < 8; ++j) v[j] = 0.5f * (v[2 * j] + v[2 * j + 1]);
  for (int j = 0; j < 8; ++j) x[((size_t)(b * NN + 8 + j)) * DD + d] = v[j] + enc_val(8 + j, d);
  for (int j = 0; j < 4; ++j) v[j] = 0.5f * (v[2 * j] + v[2 * j + 1]);
  for (int j = 0; j < 4; ++j) x[((size_t)(b * NN + 4 + j)) * DD + d] = v[j] + enc_val(4 + j, d);
  for (int j = 0; j < 2; ++j) v[j] = 0.5f * (v[2 * j] + v[2 * j + 1]);
  for (int j = 0; j < 2; ++j) x[((size_t)(b * NN + 2 + j)) * DD + d] = v[j] + enc_val(2 + j, d);
  v[0] = 0.5f * (v[0] + v[1]);
  x[((size_t)(b * NN + 1)) * DD + d] = v[0] + enc_val(1, d);
  x[((size_t)(b * NN + 0)) * DD + d] = -1.0f + enc_val(0, d);
}

// ---------------------------------------------------------------------------
// LayerNorm + exact GELU. One wave per row; lane handles dims d and d+64.
__global__ __launch_bounds__(256) void k_lngelu(const float* __restrict__ x,
                                                float* __restrict__ h,
                                                const float* __restrict__ gamma,
                                                const float* __restrict__ beta) {
  int wave = threadIdx.x >> 6, lane = threadIdx.x & 63;
  int row = blockIdx.x * 4 + wave;
  const float* xr = x + (size_t)row * DD;
  float v0 = xr[lane], v1 = xr[lane + 64];
  float s = v0 + v1;
  for (int o = 32; o; o >>= 1) s += __shfl_xor(s, o);
  float mu = s * (1.0f / 128.0f);
  float d0 = v0 - mu, d1 = v1 - mu;
  float vs = d0 * d0 + d1 * d1;
  for (int o = 32; o; o >>= 1) vs += __shfl_xor(vs, o);
  float r = rsqrtf(vs * (1.0f / 128.0f) + 1e-5f);
  float h0 = d0 * r * gamma[lane] + beta[lane];
  float h1 = d1 * r * gamma[lane + 64] + beta[lane + 64];
  h0 = 0.5f * h0 * (1.0f + erff(h0 * 0.70710678118f));
  h1 = 0.5f * h1 * (1.0f + erff(h1 * 0.70710678118f));
  h[(size_t)row * DD + lane] = h0;
  h[(size_t)row * DD + lane + 64] = h1;
}

// ---------------------------------------------------------------------------
// CSR mean aggregation: one block per destination row, 128 threads = dims.
__global__ __launch_bounds__(128) void k_agg(const float* __restrict__ h,
                                             const int* __restrict__ src,
                                             const int* __restrict__ s0a,
                                             const int* __restrict__ s1a,
                                             float* __restrict__ agg) {
  int r = blockIdx.x, d = threadIdx.x;
  int s0 = s0a[r], s1 = s1a[r];
  float a0 = 0, a1 = 0, a2 = 0, a3 = 0;
  int e = s0;
  for (; e + 4 <= s1; e += 4) {
    a0 += h[(size_t)src[e] * DD + d];
    a1 += h[(size_t)src[e + 1] * DD + d];
    a2 += h[(size_t)src[e + 2] * DD + d];
    a3 += h[(size_t)src[e + 3] * DD + d];
  }
  for (; e < s1; ++e) a0 += h[(size_t)src[e] * DD + d];
  int cnt = s1 - s0;
  float inv = 1.0f / (float)(cnt > 0 ? cnt : 1);
  agg[(size_t)r * DD + d] = (a0 + a1 + a2 + a3) * inv;
}

// ---------------------------------------------------------------------------
// x += agg @ Wn + b + h @ Wr.  64 rows per block, K chunked by 32, all
// operands staged in LDS (~49.6 KB -> 3 blocks/CU). Thread: 8 rows x 4 cols.
__global__ __launch_bounds__(256) void k_gemm(const float* __restrict__ agg,
                                              const float* __restrict__ h,
                                              const float* __restrict__ wn,
                                              const float* __restrict__ wr,
                                              const float* __restrict__ bn,
                                              float* __restrict__ x) {
  __shared__ float sA[64][33];
  __shared__ float sH[64][33];
  __shared__ float sW[2][32][DD];
  int r0 = blockIdx.x * 64;
  int tx = threadIdx.x & 31, ty = threadIdx.x >> 5;
  int c0 = tx * 4;
  float4 acc[8];
#pragma unroll
  for (int i = 0; i < 8; ++i) acc[i] = make_float4(0.f, 0.f, 0.f, 0.f);

  for (int kc = 0; kc < 4; ++kc) {
    int k0 = kc * 32;
#pragma unroll
    for (int j = 0; j < 2; ++j) {           // 512 float4s each for A and H
      int idx = threadIdx.x + j * 256;
      int row = idx >> 3, kq = idx & 7;
      float4 a = *(const float4*)&agg[(size_t)(r0 + row) * DD + k0 + kq * 4];
      float4 hh = *(const float4*)&h[(size_t)(r0 + row) * DD + k0 + kq * 4];
      sA[row][kq * 4 + 0] = a.x; sA[row][kq * 4 + 1] = a.y;
      sA[row][kq * 4 + 2] = a.z; sA[row][kq * 4 + 3] = a.w;
      sH[row][kq * 4 + 0] = hh.x; sH[row][kq * 4 + 1] = hh.y;
      sH[row][kq * 4 + 2] = hh.z; sH[row][kq * 4 + 3] = hh.w;
    }
#pragma unroll
    for (int j = 0; j < 4; ++j) {           // 1024 float4s per weight matrix
      int idx = threadIdx.x + j * 256;
      int k = idx >> 5, cq = idx & 31;
      ((float4*)&sW[0][k][0])[cq] = *(const float4*)&wn[(size_t)(k0 + k) * DD + cq * 4];
      ((float4*)&sW[1][k][0])[cq] = *(const float4*)&wr[(size_t)(k0 + k) * DD + cq * 4];
    }
    __syncthreads();
#pragma unroll 4
    for (int kk = 0; kk < 32; ++kk) {
      float4 w0 = *(const float4*)&sW[0][kk][c0];
      float4 w1 = *(const float4*)&sW[1][kk][c0];
#pragma unroll
      for (int rr = 0; rr < 8; ++rr) {
        float a = sA[ty * 8 + rr][kk];
        float hh = sH[ty * 8 + rr][kk];
        acc[rr].x += a * w0.x + hh * w1.x;
        acc[rr].y += a * w0.y + hh * w1.y;
        acc[rr].z += a * w0.z + hh * w1.z;
        acc[rr].w += a * w0.w + hh * w1.w;
      }
    }
    __syncthreads();
  }
  float4 bv = *(const float4*)&bn[c0];
#pragma unroll
  for (int rr = 0; rr < 8; ++rr) {
    int r = r0 + ty * 8 + rr;
    float4* xp = (float4*)&x[(size_t)r * DD + c0];
    float4 xv = *xp;
    xv.x += acc[rr].x + bv.x;
    xv.y += acc[rr].y + bv.y;
    xv.z += acc[rr].z + bv.z;
    xv.w += acc[rr].w + bv.w;
    *xp = xv;
  }
}

// ---------------------------------------------------------------------------
extern "C" void kernel_launch(void* const* d_in, const int* in_sizes, int n_in,
                              void* d_out, int out_size, void* d_ws, size_t ws_size,
                              hipStream_t stream) {
  const float* elements = (const float*)d_in[0];
  const float* ln_gamma = (const float*)d_in[1];
  const float* ln_beta  = (const float*)d_in[2];
  const float* w_nei    = (const float*)d_in[3];
  const float* b_nei    = (const float*)d_in[4];
  const float* w_root   = (const float*)d_in[5];
  const int*   edge     = (const int*)d_in[6];
  int E = in_sizes[6] / 2;
  const int* srcv = edge;
  const int* dstv = edge + E;
  float* x = (float*)d_out;

  char* ws = (char*)d_ws;
  int*   s0   = (int*)ws;                          // 16384 ints (64 KB)
  int*   s1   = (int*)(ws + 65536);                // 16384 ints (64 KB)
  float* lvl4 = (float*)(ws + 131072);             // 16384 floats (64 KB)
  float* h    = (float*)(ws + 196608);             // 8 MB
  float* agg  = (float*)(ws + 196608 + (size_t)ROWS * DD * 4);  // 8 MB

  k_csr<<<dim3((E + 255) / 256), dim3(256), 0, stream>>>(dstv, E, s0, s1);
  k_tree<<<dim3(BATCH * 16), dim3(256), 0, stream>>>(elements, x, lvl4);
  k_top<<<dim3(BATCH), dim3(128), 0, stream>>>(lvl4, x);
  for (int l = 0; l < 2; ++l) {
    k_lngelu<<<dim3(ROWS / 4), dim3(256), 0, stream>>>(x, h, ln_gamma + l * DD, ln_beta + l * DD);
    k_agg<<<dim3(ROWS), dim3(128), 0, stream>>>(h, srcv, s0, s1, agg);
    k_gemm<<<dim3(ROWS / 64), dim3(256), 0, stream>>>(agg, h, w_nei + l * DD * DD,
                                                      w_root + l * DD * DD, b_nei + l * DD, x);
  }
}

// Round 2
// 252.990 us; speedup vs baseline: 2.2558x; 2.2558x over previous
//
#include <hip/hip_runtime.h>
#include <hip/hip_bf16.h>

// Problem constants (fixed by the reference file)
#define LEAFN 1024
#define NN    2048            // nodes per batch incl. global node 0
#define BATCH 8
#define DD    128
#define ROWS  (BATCH*NN)      // 16384

// ln(10000)/32
#define LOG1E4_OVER_32 0.28782313662425575f

__device__ __forceinline__ float enc_val(int node, int d) {
  float hp, vp;
  if (node == 0) { hp = -0.5f; vp = -1.0f; }
  else {
    int v = 31 - __clz(node);
    hp = (float)(node - (1 << v));
    vp = (float)v;
  }
  float pos = (d < 64) ? hp : vp;
  int i = ((d < 64) ? d : (d - 64)) >> 1;
  float inv = expf(-(float)i * LOG1E4_OVER_32);
  float ang = pos * inv;
  return (d & 1) ? cosf(ang) : sinf(ang);
}

__device__ __forceinline__ float4 f4add2(float4 a, float4 b) {
  return make_float4(a.x + b.x, a.y + b.y, a.z + b.z, a.w + b.w);
}
__device__ __forceinline__ float4 f4add4(float4 a, float4 b, float4 c, float4 d) {
  return make_float4(a.x + b.x + c.x + d.x, a.y + b.y + c.y + d.y,
                     a.z + b.z + c.z + d.z, a.w + b.w + c.w + d.w);
}
__device__ __forceinline__ float4 f4scale(float4 a, float s) {
  return make_float4(a.x * s, a.y * s, a.z * s, a.w * s);
}

// ---------------------------------------------------------------------------
// CSR segment bounds from globally-sorted dst. Node 0 of each batch has no
// incoming edges -> set empty range explicitly (ws is poisoned 0xAA).
__global__ void k_csr(const int* __restrict__ dst, int E,
                      int* __restrict__ s0, int* __restrict__ s1) {
  int i = blockIdx.x * blockDim.x + threadIdx.x;
  if (i < BATCH) { s0[i * NN] = 0; s1[i * NN] = 0; }
  if (i >= E) return;
  int dv = dst[i];
  if (i == 0 || dst[i - 1] != dv) s0[dv] = i;
  if (i == E - 1 || dst[i + 1] != dv) s1[dv] = i + 1;
}

// ---------------------------------------------------------------------------
// Each block: one 64-leaf subtree (batch b, subtree s rooted at node 16+s).
// Reduce levels 10..4 in LDS, write x (+enc) for those nodes, stash raw
// level-4 feature for k_top.
__global__ __launch_bounds__(256) void k_tree(const float* __restrict__ elements,
                                              float* __restrict__ x,
                                              float* __restrict__ lvl4) {
  __shared__ float sm[127 * DD];   // local heap nodes 1..127, row (k-1)
  int b = blockIdx.x >> 4, s = blockIdx.x & 15;
  const float4* src = (const float4*)(elements + (size_t)(b * LEAFN + s * 64) * DD);
  for (int i = threadIdx.x; i < 2048; i += 256) {   // 2048 float4s
    int f = i * 4;
    int j = f >> 7, d = f & 127;
    *(float4*)&sm[(63 + j) * DD + d] = src[i];
  }
  __syncthreads();
  for (int lv = 5; lv >= 0; --lv) {
    int nodes = 1 << lv;
    for (int idx = threadIdx.x; idx < nodes * DD; idx += 256) {
      int k = nodes + (idx >> 7);
      int d = idx & 127;
      sm[(k - 1) * DD + d] = 0.5f * (sm[(2 * k - 1) * DD + d] + sm[(2 * k) * DD + d]);
    }
    __syncthreads();
  }
  for (int idx = threadIdx.x; idx < 127 * DD; idx += 256) {
    int k = (idx >> 7) + 1;
    int d = idx & 127;
    int lv = 31 - __clz(k);
    int g = ((16 + s) << lv) | (k - (1 << lv));
    x[((size_t)(b * NN + g)) * DD + d] = sm[idx] + enc_val(g, d);
  }
  if (threadIdx.x < DD) lvl4[(b * 16 + s) * DD + threadIdx.x] = sm[threadIdx.x];
}

// ---------------------------------------------------------------------------
// Finish nodes 0..15 per batch from the 16 level-4 feats.
__global__ void k_top(const float* __restrict__ lvl4, float* __restrict__ x) {
  int b = blockIdx.x, d = threadIdx.x;   // 128 threads
  float v[16];
  for (int j = 0; j < 16; ++j) v[j] = lvl4[(b * 16 + j) * DD + d];
  for (int j = 0; j < 8; ++j) v[j] = 0.5f * (v[2 * j] + v[2 * j + 1]);
  for (int j = 0; j < 8; ++j) x[((size_t)(b * NN + 8 + j)) * DD + d] = v[j] + enc_val(8 + j, d);
  for (int j = 0; j < 4; ++j) v[j] = 0.5f * (v[2 * j] + v[2 * j + 1]);
  for (int j = 0; j < 4; ++j) x[((size_t)(b * NN + 4 + j)) * DD + d] = v[j] + enc_val(4 + j, d);
  for (int j = 0; j < 2; ++j) v[j] = 0.5f * (v[2 * j] + v[2 * j + 1]);
  for (int j = 0; j < 2; ++j) x[((size_t)(b * NN + 2 + j)) * DD + d] = v[j] + enc_val(2 + j, d);
  v[0] = 0.5f * (v[0] + v[1]);
  x[((size_t)(b * NN + 1)) * DD + d] = v[0] + enc_val(1, d);
  x[((size_t)(b * NN + 0)) * DD + d] = -1.0f + enc_val(0, d);
}

// ---------------------------------------------------------------------------
// LayerNorm + exact GELU. One wave per row; lane handles dims d and d+64.
__global__ __launch_bounds__(256) void k_lngelu(const float* __restrict__ x,
                                                float* __restrict__ h,
                                                const float* __restrict__ gamma,
                                                const float* __restrict__ beta) {
  int wave = threadIdx.x >> 6, lane = threadIdx.x & 63;
  int row = blockIdx.x * 4 + wave;
  const float* xr = x + (size_t)row * DD;
  float v0 = xr[lane], v1 = xr[lane + 64];
  float s = v0 + v1;
  for (int o = 32; o; o >>= 1) s += __shfl_xor(s, o);
  float mu = s * (1.0f / 128.0f);
  float d0 = v0 - mu, d1 = v1 - mu;
  float vs = d0 * d0 + d1 * d1;
  for (int o = 32; o; o >>= 1) vs += __shfl_xor(vs, o);
  float r = rsqrtf(vs * (1.0f / 128.0f) + 1e-5f);
  float h0 = d0 * r * gamma[lane] + beta[lane];
  float h1 = d1 * r * gamma[lane + 64] + beta[lane + 64];
  h0 = 0.5f * h0 * (1.0f + erff(h0 * 0.70710678118f));
  h1 = 0.5f * h1 * (1.0f + erff(h1 * 0.70710678118f));
  h[(size_t)row * DD + lane] = h0;
  h[(size_t)row * DD + lane + 64] = h1;
}

// ---------------------------------------------------------------------------
// Internal-node aggregation, part 1: per 64-leaf subtree (block = (b, s)),
// bottom-up subtree sums S(k) = h(2k)+h(2k+1)+S(2k)+S(2k+1). Writes
// agg = S/deg for global internal nodes at depth 4..9, and S(16+s) to sroot.
__global__ __launch_bounds__(256) void k_aggsub(const float* __restrict__ h,
                                                const int* __restrict__ s0a,
                                                const int* __restrict__ s1a,
                                                float* __restrict__ agg,
                                                float* __restrict__ sroot) {
  __shared__ float4 S[64][32];    // S for local nodes 1..63 (float4 over D)
  int b = blockIdx.x >> 4, s = blockIdx.x & 15;
  const float4* h4 = (const float4*)h;
  float4* agg4 = (float4*)agg;

  // local level 5 parents (k=32..63): children are tree leaves (S=0)
  for (int idx = threadIdx.x; idx < 32 * 32; idx += 256) {
    int k = 32 + (idx >> 5), q = idx & 31;
    int c = (16 + s) * 64 + (2 * k - 64);           // global depth-10 child
    size_t r0 = (size_t)(b * NN + c) * 32;
    float4 v = f4add2(h4[r0 + q], h4[r0 + 32 + q]);
    S[k][q] = v;
    int g = (16 + s) * 32 + (k - 32);               // global depth-9 node
    int r = b * NN + g;
    float inv = 1.0f / (float)max(s1a[r] - s0a[r], 1);
    agg4[(size_t)r * 32 + q] = f4scale(v, inv);
  }
  __syncthreads();
  for (int lv = 4; lv >= 0; --lv) {
    int nk = 1 << lv;                               // parents k = nk..2nk-1
    for (int idx = threadIdx.x; idx < nk * 32; idx += 256) {
      int k = nk + (idx >> 5), q = idx & 31;
      int c = ((16 + s) << (lv + 1)) | (2 * k - 2 * nk);  // child global id
      size_t r0 = (size_t)(b * NN + c) * 32;
      float4 v = f4add4(h4[r0 + q], h4[r0 + 32 + q], S[2 * k][q], S[2 * k + 1][q]);
      S[k][q] = v;
      int g = ((16 + s) << lv) | (k - nk);
      int r = b * NN + g;
      float inv = 1.0f / (float)max(s1a[r] - s0a[r], 1);
      agg4[(size_t)r * 32 + q] = f4scale(v, inv);
    }
    __syncthreads();
  }
  for (int q = threadIdx.x; q < 32; q += 256)
    ((float4*)sroot)[(size_t)(b * 16 + s) * 32 + q] = S[1][q];
}

// ---------------------------------------------------------------------------
// Internal-node aggregation, part 2: one block per batch finishes nodes 1..15
// from sroot(16..31) + h(16..31); node 0 gets zeros (no incoming edges).
__global__ __launch_bounds__(256) void k_aggtop(const float* __restrict__ h,
                                                const float* __restrict__ sroot,
                                                const int* __restrict__ s0a,
                                                const int* __restrict__ s1a,
                                                float* __restrict__ agg) {
  __shared__ float4 S[16][32];    // S for nodes 1..15
  int b = blockIdx.x;
  const float4* h4 = (const float4*)h;
  const float4* sr4 = (const float4*)sroot;
  float4* agg4 = (float4*)agg;

  // k = 8..15: children 16..31 (S from sroot)
  for (int idx = threadIdx.x; idx < 8 * 32; idx += 256) {
    int k = 8 + (idx >> 5), q = idx & 31;
    size_t r0 = (size_t)(b * NN + 2 * k) * 32;
    float4 v = f4add4(h4[r0 + q], h4[r0 + 32 + q],
                      sr4[(size_t)(b * 16 + 2 * k - 16) * 32 + q],
                      sr4[(size_t)(b * 16 + 2 * k - 15) * 32 + q]);
    S[k][q] = v;
    int r = b * NN + k;
    float inv = 1.0f / (float)max(s1a[r] - s0a[r], 1);
    agg4[(size_t)r * 32 + q] = f4scale(v, inv);
  }
  __syncthreads();
  for (int lv = 2; lv >= 0; --lv) {
    int nk = 1 << lv;
    for (int idx = threadIdx.x; idx < nk * 32; idx += 256) {
      int k = nk + (idx >> 5), q = idx & 31;
      size_t r0 = (size_t)(b * NN + 2 * k) * 32;
      float4 v = f4add4(h4[r0 + q], h4[r0 + 32 + q], S[2 * k][q], S[2 * k + 1][q]);
      S[k][q] = v;
      int r = b * NN + k;
      float inv = 1.0f / (float)max(s1a[r] - s0a[r], 1);
      agg4[(size_t)r * 32 + q] = f4scale(v, inv);
    }
    __syncthreads();
  }
  // node 0: empty segment, deg clamps to 1 -> agg = 0
  for (int q = threadIdx.x; q < 32; q += 256)
    agg4[(size_t)(b * NN) * 32 + q] = make_float4(0.f, 0.f, 0.f, 0.f);
}

// ---------------------------------------------------------------------------
// Leaf-row aggregation (uniform ~40 edges/row): one block per leaf row.
__global__ __launch_bounds__(128) void k_aggleaf(const float* __restrict__ h,
                                                 const int* __restrict__ src,
                                                 const int* __restrict__ s0a,
                                                 const int* __restrict__ s1a,
                                                 float* __restrict__ agg) {
  int blk = blockIdx.x;
  int b = blk >> 10, li = blk & 1023;
  int r = b * NN + LEAFN + li;
  int d = threadIdx.x;
  int s0 = s0a[r], s1 = s1a[r];
  float a0 = 0, a1 = 0, a2 = 0, a3 = 0;
  int e = s0;
  for (; e + 4 <= s1; e += 4) {
    a0 += h[(size_t)src[e] * DD + d];
    a1 += h[(size_t)src[e + 1] * DD + d];
    a2 += h[(size_t)src[e + 2] * DD + d];
    a3 += h[(size_t)src[e + 3] * DD + d];
  }
  for (; e < s1; ++e) a0 += h[(size_t)src[e] * DD + d];
  int cnt = s1 - s0;
  float inv = 1.0f / (float)(cnt > 0 ? cnt : 1);
  agg[(size_t)r * DD + d] = (a0 + a1 + a2 + a3) * inv;
}

// ---------------------------------------------------------------------------
// x += agg @ Wn + b + h @ Wr.  64 rows per block, K chunked by 32, all
// operands staged in LDS (~49.6 KB -> 3 blocks/CU). Thread: 8 rows x 4 cols.
__global__ __launch_bounds__(256) void k_gemm(const float* __restrict__ agg,
                                              const float* __restrict__ h,
                                              const float* __restrict__ wn,
                                              const float* __restrict__ wr,
                                              const float* __restrict__ bn,
                                              float* __restrict__ x) {
  __shared__ float sA[64][33];
  __shared__ float sH[64][33];
  __shared__ float sW[2][32][DD];
  int r0 = blockIdx.x * 64;
  int tx = threadIdx.x & 31, ty = threadIdx.x >> 5;
  int c0 = tx * 4;
  float4 acc[8];
#pragma unroll
  for (int i = 0; i < 8; ++i) acc[i] = make_float4(0.f, 0.f, 0.f, 0.f);

  for (int kc = 0; kc < 4; ++kc) {
    int k0 = kc * 32;
#pragma unroll
    for (int j = 0; j < 2; ++j) {
      int idx = threadIdx.x + j * 256;
      int row = idx >> 3, kq = idx & 7;
      float4 a = *(const float4*)&agg[(size_t)(r0 + row) * DD + k0 + kq * 4];
      float4 hh = *(const float4*)&h[(size_t)(r0 + row) * DD + k0 + kq * 4];
      sA[row][kq * 4 + 0] = a.x; sA[row][kq * 4 + 1] = a.y;
      sA[row][kq * 4 + 2] = a.z; sA[row][kq * 4 + 3] = a.w;
      sH[row][kq * 4 + 0] = hh.x; sH[row][kq * 4 + 1] = hh.y;
      sH[row][kq * 4 + 2] = hh.z; sH[row][kq * 4 + 3] = hh.w;
    }
#pragma unroll
    for (int j = 0; j < 4; ++j) {
      int idx = threadIdx.x + j * 256;
      int k = idx >> 5, cq = idx & 31;
      ((float4*)&sW[0][k][0])[cq] = *(const float4*)&wn[(size_t)(k0 + k) * DD + cq * 4];
      ((float4*)&sW[1][k][0])[cq] = *(const float4*)&wr[(size_t)(k0 + k) * DD + cq * 4];
    }
    __syncthreads();
#pragma unroll 4
    for (int kk = 0; kk < 32; ++kk) {
      float4 w0 = *(const float4*)&sW[0][kk][c0];
      float4 w1 = *(const float4*)&sW[1][kk][c0];
#pragma unroll
      for (int rr = 0; rr < 8; ++rr) {
        float a = sA[ty * 8 + rr][kk];
        float hh = sH[ty * 8 + rr][kk];
        acc[rr].x += a * w0.x + hh * w1.x;
        acc[rr].y += a * w0.y + hh * w1.y;
        acc[rr].z += a * w0.z + hh * w1.z;
        acc[rr].w += a * w0.w + hh * w1.w;
      }
    }
    __syncthreads();
  }
  float4 bv = *(const float4*)&bn[c0];
#pragma unroll
  for (int rr = 0; rr < 8; ++rr) {
    int r = r0 + ty * 8 + rr;
    float4* xp = (float4*)&x[(size_t)r * DD + c0];
    float4 xv = *xp;
    xv.x += acc[rr].x + bv.x;
    xv.y += acc[rr].y + bv.y;
    xv.z += acc[rr].z + bv.z;
    xv.w += acc[rr].w + bv.w;
    *xp = xv;
  }
}

// ---------------------------------------------------------------------------
extern "C" void kernel_launch(void* const* d_in, const int* in_sizes, int n_in,
                              void* d_out, int out_size, void* d_ws, size_t ws_size,
                              hipStream_t stream) {
  const float* elements = (const float*)d_in[0];
  const float* ln_gamma = (const float*)d_in[1];
  const float* ln_beta  = (const float*)d_in[2];
  const float* w_nei    = (const float*)d_in[3];
  const float* b_nei    = (const float*)d_in[4];
  const float* w_root   = (const float*)d_in[5];
  const int*   edge     = (const int*)d_in[6];
  int E = in_sizes[6] / 2;
  const int* srcv = edge;
  const int* dstv = edge + E;
  float* x = (float*)d_out;

  char* ws = (char*)d_ws;
  int*   s0    = (int*)ws;                          // 64 KB
  int*   s1    = (int*)(ws + 65536);                // 64 KB
  float* lvl4  = (float*)(ws + 131072);             // 64 KB
  float* sroot = (float*)(ws + 196608);             // 16*8*128 floats (64 KB)
  float* h     = (float*)(ws + 262144);             // 8 MB
  float* agg   = (float*)(ws + 262144 + (size_t)ROWS * DD * 4);  // 8 MB

  k_csr<<<dim3((E + 255) / 256), dim3(256), 0, stream>>>(dstv, E, s0, s1);
  k_tree<<<dim3(BATCH * 16), dim3(256), 0, stream>>>(elements, x, lvl4);
  k_top<<<dim3(BATCH), dim3(128), 0, stream>>>(lvl4, x);
  for (int l = 0; l < 2; ++l) {
    k_lngelu<<<dim3(ROWS / 4), dim3(256), 0, stream>>>(x, h, ln_gamma + l * DD, ln_beta + l * DD);
    k_aggsub<<<dim3(BATCH * 16), dim3(256), 0, stream>>>(h, s0, s1, agg, sroot);
    k_aggtop<<<dim3(BATCH), dim3(256), 0, stream>>>(h, sroot, s0, s1, agg);
    k_aggleaf<<<dim3(BATCH * LEAFN), dim3(128), 0, stream>>>(h, srcv, s0, s1, agg);
    k_gemm<<<dim3(ROWS / 64), dim3(256), 0, stream>>>(agg, h, w_nei + l * DD * DD,
                                                      w_root + l * DD * DD, b_nei + l * DD, x);
  }
}

// Round 3
// 229.300 us; speedup vs baseline: 2.4888x; 1.1033x over previous
//
#include <hip/hip_runtime.h>
#include <hip/hip_bf16.h>

// Problem constants (fixed by the reference file)
#define LEAFN 1024
#define NN    2048            // nodes per batch incl. global node 0
#define BATCH 8
#define DD    128
#define ROWS  (BATCH*NN)      // 16384
#define AHS   256             // ah row stride: [agg(128) | h(128)] bf16

// ln(10000)/32
#define LOG1E4_OVER_32 0.28782313662425575f

typedef __bf16 bf16x8 __attribute__((ext_vector_type(8)));
typedef float  floatx4 __attribute__((ext_vector_type(4)));

__device__ __forceinline__ float bf2f(unsigned short u) {
  return __uint_as_float(((unsigned)u) << 16);
}
__device__ __forceinline__ unsigned short f2bf(float f) {
  unsigned u = __float_as_uint(f);
  u += 0x7FFFu + ((u >> 16) & 1u);          // round-to-nearest-even
  return (unsigned short)(u >> 16);
}

__device__ __forceinline__ float enc_val(int node, int d) {
  float hp, vp;
  if (node == 0) { hp = -0.5f; vp = -1.0f; }
  else {
    int v = 31 - __clz(node);
    hp = (float)(node - (1 << v));
    vp = (float)v;
  }
  float pos = (d < 64) ? hp : vp;
  int i = ((d < 64) ? d : (d - 64)) >> 1;
  float inv = expf(-(float)i * LOG1E4_OVER_32);
  float ang = pos * inv;
  return (d & 1) ? cosf(ang) : sinf(ang);
}

// ---------------------------------------------------------------------------
// CSR segment bounds from globally-sorted dst (node 0 per batch: empty).
__global__ void k_csr(const int* __restrict__ dst, int E,
                      int* __restrict__ s0, int* __restrict__ s1) {
  int i = blockIdx.x * blockDim.x + threadIdx.x;
  if (i < BATCH) { s0[i * NN] = 0; s1[i * NN] = 0; }
  if (i >= E) return;
  int dv = dst[i];
  if (i == 0 || dst[i - 1] != dv) s0[dv] = i;
  if (i == E - 1 || dst[i + 1] != dv) s1[dv] = i + 1;
}

// ---------------------------------------------------------------------------
// Weight repack into B-fragment order for mfma_f32_16x16x32_bf16.
// Wcat[k][n], k in [0,256): rows 0..127 = w_nei[l], 128..255 = w_root[l].
// Frag (kc, ct): lane holds B[k = kc*32 + (lane>>4)*8 + j][n = ct*16 + (lane&15)].
__global__ __launch_bounds__(256) void k_repack(const float* __restrict__ wn,
                                                const float* __restrict__ wr,
                                                unsigned short* __restrict__ wf) {
  int l = blockIdx.y;
  int idx = blockIdx.x * 256 + threadIdx.x;   // 0..4095
  int lane = idx & 63, ct = (idx >> 6) & 7, kc = idx >> 9;
  int n = ct * 16 + (lane & 15);
  int k = kc * 32 + (lane >> 4) * 8;
  const float* w = (k < 128) ? (wn + (size_t)l * DD * DD) : (wr + (size_t)l * DD * DD);
  int kk = k & 127;
  unsigned short* o = wf + (size_t)l * 32768 + (size_t)idx * 8;
#pragma unroll
  for (int j = 0; j < 8; ++j) o[j] = f2bf(w[(size_t)(kk + j) * DD + n]);
}

// ---------------------------------------------------------------------------
// Tree build: block = 64-leaf subtree (b, s rooted at 16+s). Writes x (+enc)
// for depth 4..10 nodes, stashes raw level-4 feats.
__global__ __launch_bounds__(256) void k_tree(const float* __restrict__ elements,
                                              float* __restrict__ x,
                                              float* __restrict__ lvl4) {
  __shared__ float sm[127 * DD];
  int b = blockIdx.x >> 4, s = blockIdx.x & 15;
  const float4* src = (const float4*)(elements + (size_t)(b * LEAFN + s * 64) * DD);
  for (int i = threadIdx.x; i < 2048; i += 256) {
    int f = i * 4;
    int j = f >> 7, d = f & 127;
    *(float4*)&sm[(63 + j) * DD + d] = src[i];
  }
  __syncthreads();
  for (int lv = 5; lv >= 0; --lv) {
    int nodes = 1 << lv;
    for (int idx = threadIdx.x; idx < nodes * DD; idx += 256) {
      int k = nodes + (idx >> 7);
      int d = idx & 127;
      sm[(k - 1) * DD + d] = 0.5f * (sm[(2 * k - 1) * DD + d] + sm[(2 * k) * DD + d]);
    }
    __syncthreads();
  }
  for (int idx = threadIdx.x; idx < 127 * DD; idx += 256) {
    int k = (idx >> 7) + 1;
    int d = idx & 127;
    int lv = 31 - __clz(k);
    int g = ((16 + s) << lv) | (k - (1 << lv));
    x[((size_t)(b * NN + g)) * DD + d] = sm[idx] + enc_val(g, d);
  }
  if (threadIdx.x < DD) lvl4[(b * 16 + s) * DD + threadIdx.x] = sm[threadIdx.x];
}

// ---------------------------------------------------------------------------
// Finish nodes 0..15 per batch.
__global__ void k_top(const float* __restrict__ lvl4, float* __restrict__ x) {
  int b = blockIdx.x, d = threadIdx.x;   // 128 threads
  float v[16];
  for (int j = 0; j < 16; ++j) v[j] = lvl4[(b * 16 + j) * DD + d];
  for (int j = 0; j < 8; ++j) v[j] = 0.5f * (v[2 * j] + v[2 * j + 1]);
  for (int j = 0; j < 8; ++j) x[((size_t)(b * NN + 8 + j)) * DD + d] = v[j] + enc_val(8 + j, d);
  for (int j = 0; j < 4; ++j) v[j] = 0.5f * (v[2 * j] + v[2 * j + 1]);
  for (int j = 0; j < 4; ++j) x[((size_t)(b * NN + 4 + j)) * DD + d] = v[j] + enc_val(4 + j, d);
  for (int j = 0; j < 2; ++j) v[j] = 0.5f * (v[2 * j] + v[2 * j + 1]);
  for (int j = 0; j < 2; ++j) x[((size_t)(b * NN + 2 + j)) * DD + d] = v[j] + enc_val(2 + j, d);
  v[0] = 0.5f * (v[0] + v[1]);
  x[((size_t)(b * NN + 1)) * DD + d] = v[0] + enc_val(1, d);
  x[((size_t)(b * NN + 0)) * DD + d] = -1.0f + enc_val(0, d);
}

// ---------------------------------------------------------------------------
// LayerNorm + exact GELU -> bf16 h into ah[row][128..255].
__global__ __launch_bounds__(256) void k_lngelu(const float* __restrict__ x,
                                                unsigned short* __restrict__ ah,
                                                const float* __restrict__ gamma,
                                                const float* __restrict__ beta) {
  int wave = threadIdx.x >> 6, lane = threadIdx.x & 63;
  int row = blockIdx.x * 4 + wave;
  const float* xr = x + (size_t)row * DD;
  float v0 = xr[lane], v1 = xr[lane + 64];
  float s = v0 + v1;
  for (int o = 32; o; o >>= 1) s += __shfl_xor(s, o);
  float mu = s * (1.0f / 128.0f);
  float d0 = v0 - mu, d1 = v1 - mu;
  float vs = d0 * d0 + d1 * d1;
  for (int o = 32; o; o >>= 1) vs += __shfl_xor(vs, o);
  float r = rsqrtf(vs * (1.0f / 128.0f) + 1e-5f);
  float h0 = d0 * r * gamma[lane] + beta[lane];
  float h1 = d1 * r * gamma[lane + 64] + beta[lane + 64];
  h0 = 0.5f * h0 * (1.0f + erff(h0 * 0.70710678118f));
  h1 = 0.5f * h1 * (1.0f + erff(h1 * 0.70710678118f));
  ah[(size_t)row * AHS + 128 + lane] = f2bf(h0);
  ah[(size_t)row * AHS + 192 + lane] = f2bf(h1);
}

// ---------------------------------------------------------------------------
// Internal-node aggregation part 1: subtree sums per 64-leaf subtree.
// Reads bf16 h from ah[.][128..], writes bf16 agg to ah[.][0..128), S(16+s)->sroot.
__global__ __launch_bounds__(256) void k_aggsub(unsigned short* ah,
                                                const int* __restrict__ s0a,
                                                const int* __restrict__ s1a,
                                                float* __restrict__ sroot) {
  __shared__ floatx4 S[64][32];
  int b = blockIdx.x >> 4, s = blockIdx.x & 15;

  for (int idx = threadIdx.x; idx < 32 * 32; idx += 256) {
    int k = 32 + (idx >> 5), q = idx & 31;
    int c = (16 + s) * 64 + (2 * k - 64);           // global depth-10 child
    size_t a0 = (size_t)(b * NN + c) * AHS + 128 + q * 4;
    ushort4 u0 = *(const ushort4*)&ah[a0];
    ushort4 u1 = *(const ushort4*)&ah[a0 + AHS];
    floatx4 v;
    v[0] = bf2f(u0.x) + bf2f(u1.x);
    v[1] = bf2f(u0.y) + bf2f(u1.y);
    v[2] = bf2f(u0.z) + bf2f(u1.z);
    v[3] = bf2f(u0.w) + bf2f(u1.w);
    S[k][q] = v;
    int g = (16 + s) * 32 + (k - 32);
    int r = b * NN + g;
    float inv = 1.0f / (float)max(s1a[r] - s0a[r], 1);
    ushort4 o;
    o.x = f2bf(v[0] * inv); o.y = f2bf(v[1] * inv);
    o.z = f2bf(v[2] * inv); o.w = f2bf(v[3] * inv);
    *(ushort4*)&ah[(size_t)r * AHS + q * 4] = o;
  }
  __syncthreads();
  for (int lv = 4; lv >= 0; --lv) {
    int nk = 1 << lv;
    for (int idx = threadIdx.x; idx < nk * 32; idx += 256) {
      int k = nk + (idx >> 5), q = idx & 31;
      int c = ((16 + s) << (lv + 1)) | (2 * k - 2 * nk);
      size_t a0 = (size_t)(b * NN + c) * AHS + 128 + q * 4;
      ushort4 u0 = *(const ushort4*)&ah[a0];
      ushort4 u1 = *(const ushort4*)&ah[a0 + AHS];
      floatx4 sc0 = S[2 * k][q], sc1 = S[2 * k + 1][q];
      floatx4 v;
      v[0] = bf2f(u0.x) + bf2f(u1.x) + sc0[0] + sc1[0];
      v[1] = bf2f(u0.y) + bf2f(u1.y) + sc0[1] + sc1[1];
      v[2] = bf2f(u0.z) + bf2f(u1.z) + sc0[2] + sc1[2];
      v[3] = bf2f(u0.w) + bf2f(u1.w) + sc0[3] + sc1[3];
      S[k][q] = v;
      int g = ((16 + s) << lv) | (k - nk);
      int r = b * NN + g;
      float inv = 1.0f / (float)max(s1a[r] - s0a[r], 1);
      ushort4 o;
      o.x = f2bf(v[0] * inv); o.y = f2bf(v[1] * inv);
      o.z = f2bf(v[2] * inv); o.w = f2bf(v[3] * inv);
      *(ushort4*)&ah[(size_t)r * AHS + q * 4] = o;
    }
    __syncthreads();
  }
  for (int q = threadIdx.x; q < 32; q += 256)
    ((floatx4*)sroot)[(size_t)(b * 16 + s) * 32 + q] = S[1][q];
}

// ---------------------------------------------------------------------------
// Part 2 fused: blocks 0..8191 = leaf-row gather; blocks 8192..8199 = top
// nodes 0..15 per batch (from sroot + h).
__global__ __launch_bounds__(128) void k_aggrest(const int* __restrict__ src,
                                                 const int* __restrict__ s0a,
                                                 const int* __restrict__ s1a,
                                                 const float* __restrict__ sroot,
                                                 unsigned short* ah) {
  int blk = blockIdx.x, d = threadIdx.x;
  if (blk < BATCH * LEAFN) {
    int b = blk >> 10, li = blk & 1023;
    int r = b * NN + LEAFN + li;
    int s0 = s0a[r], s1 = s1a[r];
    float a0 = 0, a1 = 0, a2 = 0, a3 = 0;
    int e = s0;
    for (; e + 4 <= s1; e += 4) {
      a0 += bf2f(ah[(size_t)src[e] * AHS + 128 + d]);
      a1 += bf2f(ah[(size_t)src[e + 1] * AHS + 128 + d]);
      a2 += bf2f(ah[(size_t)src[e + 2] * AHS + 128 + d]);
      a3 += bf2f(ah[(size_t)src[e + 3] * AHS + 128 + d]);
    }
    for (; e < s1; ++e) a0 += bf2f(ah[(size_t)src[e] * AHS + 128 + d]);
    float inv = 1.0f / (float)max(s1 - s0, 1);
    ah[(size_t)r * AHS + d] = f2bf((a0 + a1 + a2 + a3) * inv);
  } else {
    int b = blk - BATCH * LEAFN;
    float S16[16], h16[16], Sv[16];
#pragma unroll
    for (int j = 0; j < 16; ++j) S16[j] = sroot[(size_t)(b * 16 + j) * DD + d];
#pragma unroll
    for (int j = 0; j < 16; ++j)
      h16[j] = bf2f(ah[(size_t)(b * NN + 16 + j) * AHS + 128 + d]);
#pragma unroll
    for (int k = 8; k < 16; ++k)
      Sv[k] = h16[2 * k - 16] + h16[2 * k - 15] + S16[2 * k - 16] + S16[2 * k - 15];
#pragma unroll
    for (int k = 7; k >= 1; --k)
      Sv[k] = bf2f(ah[(size_t)(b * NN + 2 * k) * AHS + 128 + d]) +
              bf2f(ah[(size_t)(b * NN + 2 * k + 1) * AHS + 128 + d]) +
              Sv[2 * k] + Sv[2 * k + 1];
#pragma unroll
    for (int k = 1; k < 16; ++k) {
      int r = b * NN + k;
      float inv = 1.0f / (float)max(s1a[r] - s0a[r], 1);
      ah[(size_t)r * AHS + d] = f2bf(Sv[k] * inv);
    }
    ah[(size_t)(b * NN) * AHS + d] = f2bf(0.0f);   // node 0: no in-edges
  }
}

// ---------------------------------------------------------------------------
// x += [agg|h] @ [Wn;Wr] + bias, bf16 MFMA, no LDS. Block = 128 rows (4 waves
// x 32 rows), full 128-col width. Per wave: 2 m-tiles x 8 n-tiles x 8 k-chunks.
__global__ __launch_bounds__(256) void k_gemm(const unsigned short* __restrict__ ah,
                                              const unsigned short* __restrict__ wfl,
                                              const float* __restrict__ bn,
                                              float* __restrict__ x) {
  int wave = threadIdx.x >> 6, lane = threadIdx.x & 63;
  int r0 = blockIdx.x * 128 + wave * 32;
  int m = lane & 15, q = lane >> 4;
  const bf16x8* A0 = (const bf16x8*)(ah + (size_t)(r0 + m) * AHS + q * 8);
  const bf16x8* A1 = (const bf16x8*)(ah + (size_t)(r0 + 16 + m) * AHS + q * 8);
  const bf16x8* B  = (const bf16x8*)wfl + lane;
  floatx4 acc[2][8];
#pragma unroll
  for (int i = 0; i < 2; ++i)
#pragma unroll
    for (int ct = 0; ct < 8; ++ct) acc[i][ct] = (floatx4){0.f, 0.f, 0.f, 0.f};

#pragma unroll
  for (int kc = 0; kc < 8; ++kc) {
    bf16x8 a0 = A0[kc * 4];
    bf16x8 a1 = A1[kc * 4];
#pragma unroll
    for (int ct = 0; ct < 8; ++ct) {
      bf16x8 bb = B[(kc * 8 + ct) * 64];
      acc[0][ct] = __builtin_amdgcn_mfma_f32_16x16x32_bf16(a0, bb, acc[0][ct], 0, 0, 0);
      acc[1][ct] = __builtin_amdgcn_mfma_f32_16x16x32_bf16(a1, bb, acc[1][ct], 0, 0, 0);
    }
  }
#pragma unroll
  for (int i = 0; i < 2; ++i)
#pragma unroll
    for (int ct = 0; ct < 8; ++ct) {
      int col = ct * 16 + m;
      float bias = bn[col];
#pragma unroll
      for (int r = 0; r < 4; ++r) {
        int row = r0 + i * 16 + q * 4 + r;
        x[(size_t)row * DD + col] += acc[i][ct][r] + bias;
      }
    }
}

// ---------------------------------------------------------------------------
extern "C" void kernel_launch(void* const* d_in, const int* in_sizes, int n_in,
                              void* d_out, int out_size, void* d_ws, size_t ws_size,
                              hipStream_t stream) {
  const float* elements = (const float*)d_in[0];
  const float* ln_gamma = (const float*)d_in[1];
  const float* ln_beta  = (const float*)d_in[2];
  const float* w_nei    = (const float*)d_in[3];
  const float* b_nei    = (const float*)d_in[4];
  const float* w_root   = (const float*)d_in[5];
  const int*   edge     = (const int*)d_in[6];
  int E = in_sizes[6] / 2;
  const int* srcv = edge;
  const int* dstv = edge + E;
  float* x = (float*)d_out;

  char* ws = (char*)d_ws;
  int*            s0    = (int*)ws;                       // 64 KB
  int*            s1    = (int*)(ws + 65536);             // 64 KB
  float*          lvl4  = (float*)(ws + 131072);          // 64 KB
  float*          sroot = (float*)(ws + 196608);          // 64 KB
  unsigned short* wf    = (unsigned short*)(ws + 262144); // 128 KB
  unsigned short* ah    = (unsigned short*)(ws + 393216); // 8 MB

  k_csr<<<dim3((E + 255) / 256), dim3(256), 0, stream>>>(dstv, E, s0, s1);
  k_tree<<<dim3(BATCH * 16), dim3(256), 0, stream>>>(elements, x, lvl4);
  k_top<<<dim3(BATCH), dim3(128), 0, stream>>>(lvl4, x);
  k_repack<<<dim3(16, 2), dim3(256), 0, stream>>>(w_nei, w_root, wf);
  for (int l = 0; l < 2; ++l) {
    k_lngelu<<<dim3(ROWS / 4), dim3(256), 0, stream>>>(x, ah, ln_gamma + l * DD, ln_beta + l * DD);
    k_aggsub<<<dim3(BATCH * 16), dim3(256), 0, stream>>>(ah, s0, s1, sroot);
    k_aggrest<<<dim3(BATCH * LEAFN + BATCH), dim3(128), 0, stream>>>(srcv, s0, s1, sroot, ah);
    k_gemm<<<dim3(ROWS / 128), dim3(256), 0, stream>>>(ah, wf + (size_t)l * 32768,
                                                       b_nei + l * DD, x);
  }
}